// Round 3
// baseline (408.044 us; speedup 1.0000x reference)
//
#include <hip/hip_runtime.h>

#define CH    256
#define NTOK  2304
#define MATSZ (CH * NTOK)   // 589824 elements per (b, matrix)

typedef __bf16 bf16x8 __attribute__((ext_vector_type(8)));
typedef float  f4v    __attribute__((ext_vector_type(4)));
typedef unsigned int u32x4 __attribute__((ext_vector_type(4)));

__device__ __forceinline__ unsigned short f2bf(float f) {
    union { float f; unsigned int i; } c;
    c.f = f;
    unsigned int x = c.i;
    x += 0x7fffu + ((x >> 16) & 1u);   // round-to-nearest-even
    return (unsigned short)(x >> 16);
}

__device__ __forceinline__ bf16x8 cvt8(const float* p) {
    union { bf16x8 v; unsigned short s[8]; } u;
#pragma unroll
    for (int i = 0; i < 8; ++i) u.s[i] = f2bf(p[i]);
    return u.v;
}

// ---------------------------------------------------------------------------
// 64x64-tiled transpose + fp32->bf16 (unchanged — HW-verified)
// ---------------------------------------------------------------------------
__global__ __launch_bounds__(256) void tpose_k(
    const float* __restrict__ inL,
    const float* __restrict__ inR,
    unsigned short* __restrict__ out, int R, int Ccols)
{
    __shared__ unsigned short tile[64][72];
    int mat = blockIdx.y;
    const float* in = (mat >= 8 ? inR : inL) + (size_t)(mat & 7) * MATSZ;
    unsigned short* o = out + (size_t)mat * MATSZ;
    int tC = Ccols >> 6;
    int r0 = (blockIdx.x / tC) << 6;
    int c0 = (blockIdx.x % tC) << 6;
    int t = threadIdx.x;
    int col = t & 63, rs = t >> 6;
#pragma unroll
    for (int i = 0; i < 16; ++i) {
        int row = rs + i * 4;
        tile[row][col] = f2bf(in[(size_t)(r0 + row) * Ccols + c0 + col]);
    }
    __syncthreads();
#pragma unroll
    for (int i = 0; i < 16; ++i) {
        int crow = rs + i * 4;
        o[(size_t)(c0 + crow) * R + r0 + col] = tile[col][crow];
    }
}

// ---------------------------------------------------------------------------
// Projection (unchanged — HW-verified)
// ---------------------------------------------------------------------------
__global__ __launch_bounds__(256, 2) void proj_k(
    const unsigned short* __restrict__ XT,   // [2][8][2304][256] bf16
    const float* __restrict__ Wq_, const float* __restrict__ Wk_,
    const float* __restrict__ bq_, const float* __restrict__ bk_,
    const float* __restrict__ gq_, const float* __restrict__ gk_,
    const float* __restrict__ beq_, const float* __restrict__ bek_,
    const float* __restrict__ mq_, const float* __restrict__ mk_,
    const float* __restrict__ vq_, const float* __restrict__ vk_,
    unsigned short* __restrict__ Yout)       // [4][8][MATSZ] bf16
{
    __shared__ __align__(16) unsigned short Xs[64][264];
    int pb = blockIdx.y;
    int p = pb >> 3, b = pb & 7;
    int s = p & 1, br = p >> 1;
    const unsigned short* X = XT + (size_t)(s * 8 + b) * MATSZ;
    const float* W  = br ? Wk_ : Wq_;
    const float* bb = br ? bk_ : bq_;
    const float* gg = br ? gk_ : gq_;
    const float* be = br ? bek_ : beq_;
    const float* mm = br ? mk_ : mq_;
    const float* vv = br ? vk_ : vq_;
    unsigned short* Yo = Yout + (size_t)pb * MATSZ;

    int ot = blockIdx.x & 3, pt = blockIdx.x >> 2;
    int o0 = ot * 64, pos0 = pt * 64;
    int t = threadIdx.x;
    int w = t >> 6, lane = t & 63;
    int l15 = lane & 15, quad = lane >> 4;

    {   // stage XT tile: 64 pos-rows x 256 c
        int r = t >> 2, cq = (t & 3) << 6;
        const unsigned short* src = X + (size_t)(pos0 + r) * CH + cq;
        unsigned short* dst = &Xs[r][cq];
#pragma unroll
        for (int k = 0; k < 8; ++k)
            *(u32x4*)(dst + k * 8) = *(const u32x4*)(src + k * 8);
    }
    bf16x8 wf[8];
    {
        const float* wp = W + (size_t)(o0 + w * 16 + l15) * CH + quad * 8;
#pragma unroll
        for (int kc = 0; kc < 8; ++kc)
            wf[kc] = cvt8(wp + kc * 32);
    }
    __syncthreads();

    f4v zero4 = {0.f, 0.f, 0.f, 0.f};
    f4v acc[4] = {zero4, zero4, zero4, zero4};
#pragma unroll
    for (int kc = 0; kc < 8; ++kc) {
#pragma unroll
        for (int ct = 0; ct < 4; ++ct) {
            bf16x8 xb = *(const bf16x8*)(&Xs[ct * 16 + l15][kc * 32 + quad * 8]);
            acc[ct] = __builtin_amdgcn_mfma_f32_16x16x32_bf16(wf[kc], xb, acc[ct], 0, 0, 0);
        }
    }
#pragma unroll
    for (int r = 0; r < 4; ++r) {
        int o = o0 + w * 16 + quad * 4 + r;
        float scale = gg[o] * rsqrtf(vv[o] + 1e-5f);
        float shift = (bb[o] - mm[o]) * scale + be[o];
#pragma unroll
        for (int ct = 0; ct < 4; ++ct) {
            float val = acc[ct][r] * scale + shift;
            Yo[(size_t)o * NTOK + pos0 + ct * 16 + l15] = f2bf(val);
        }
    }
}

// ---------------------------------------------------------------------------
// Fused attention R3: wave-slice decomposition, no K/V LDS staging.
//  * kf/vf read DIRECT from global (L2-resident; byte-identical to what the
//    R2 staging consumed — Kp linear = [key][ch], VT = [ch][key]).
//  * QK^T: wave w = all 64 q-rows x keys [w*16, w*16+16): K read ONCE per
//    block-tile (waves disjoint). A-frags from Qs LDS (staged once, same
//    verified linear+XOR pattern as R2's Ks).
//  * PV: wave w = all 64 q-rows x channels [w*64, w*64+64): V read ONCE.
//  * P bridge: cross-wave, double-buffered [64 rows][128B] + XOR swizzle;
//    ONE __syncthreads per tile. Safety: write(kt+1) and read(kt-1) share a
//    buffer parity but are separated by barrier(kt); write(kt) vs read(kt)
//    separated by barrier(kt); write(kt+1) vs read(kt) use different bufs.
//  * Row-sums: per-lane partials in-loop; shfl(1,2,4,8) + tiny LDS cross-
//    wave reduce once after the loop.
//  * LDS 50176B (Qs 32K | Pb 16K | Ls 1K) -> 3 blocks/CU; epilogue reuses
//    [0,37376) as a [128][73] fp32 transpose buffer, two 128-channel passes.
// ---------------------------------------------------------------------------
__global__ __launch_bounds__(256, 3) void attn_k(
    const unsigned short* __restrict__ Y,    // [4][8][MATSZ] projections bf16
    const unsigned short* __restrict__ VT,   // [2][8][256][2304] bf16
    float* __restrict__ out)                 // [2][8][MATSZ] fp32
{
    __shared__ __align__(16) unsigned char lds[50176];
    unsigned char* Qs  = lds;                 // 64 x 512B, xor ((row&7)<<4)
    unsigned char* Pb0 = lds + 32768;         // 2 x (64 x 128B), xor ((row&7)<<4)
    float*         Ls  = (float*)(lds + 49152); // [4][64] cross-wave sum patch

    int bid = blockIdx.x;
    int wg = (bid & 7) * 72 + (bid >> 3);   // XCD swizzle (576 = 8*72, bijective)
    int qt = wg % 36;
    int ab = wg / 36;
    int a = ab >> 3, b = ab & 7;
    const unsigned short* Qp = Y + (size_t)(a * 8 + b) * MATSZ;        // q(l)/q(r)
    const unsigned short* Kp = Y + (size_t)((3 - a) * 8 + b) * MATSZ;  // k(r)/k(l)
    const unsigned short* Vp = VT + (size_t)((1 - a) * 8 + b) * MATSZ;
    float* Op = out + (size_t)ab * MATSZ;

    int t = threadIdx.x;
    int w = t >> 6, lane = t & 63;
    int l15 = lane & 15, quad = lane >> 4;
    int rxor = (l15 & 7) << 4;               // read-side swizzle

    // stage Q tile once: rows qt*64.. (64 x 256ch), linear + XOR (R2-verified map)
    {
        const unsigned short* qsrc = Qp + (size_t)qt * 64 * CH + t * 8;
        int qxor = ((t >> 5) & 7) << 4;      // (row&7)<<4, row = k*8 + (t>>5)
        unsigned char* qdst = Qs + ((t * 16) ^ qxor);
#pragma unroll
        for (int k = 0; k < 8; ++k)
            *(u32x4*)(qdst + k * 4096) = *(const u32x4*)(qsrc + k * 2048);
    }
    __syncthreads();

    f4v zero4 = {0.f, 0.f, 0.f, 0.f};
    f4v acc_o[4][4];                          // [qfrag f][ch-col ct2]
#pragma unroll
    for (int f = 0; f < 4; ++f)
#pragma unroll
        for (int c = 0; c < 4; ++c) acc_o[f][c] = zero4;
    float l_acc[4][4];                        // [f][r] per-lane partial sums
#pragma unroll
    for (int f = 0; f < 4; ++f)
#pragma unroll
        for (int r = 0; r < 4; ++r) l_acc[f][r] = 0.f;

    // per-thread global bases (wave-sliced)
    const unsigned short* KpT = Kp + (size_t)(w * 16 + l15) * CH + quad * 8;
    const unsigned short* VpT = Vp + (size_t)(w * 64 + l15) * NTOK + quad * 8;

    for (int kt = 0; kt < 36; ++kt) {
        // K fragments for this wave's 16 keys, direct from L2
        bf16x8 kf[8];
        {
            const unsigned short* kp = KpT + (size_t)kt * 64 * CH;
#pragma unroll
            for (int kc = 0; kc < 8; ++kc)
                kf[kc] = *(const bf16x8*)(kp + kc * 32);
        }
        // S[64 q][w's 16 keys] = Q K^T ; A-frags from swizzled Qs
        f4v accs[4] = {zero4, zero4, zero4, zero4};
#pragma unroll
        for (int kc = 0; kc < 8; ++kc) {
#pragma unroll
            for (int f = 0; f < 4; ++f) {
                bf16x8 qa = *(const bf16x8*)(Qs + ((f * 16 + l15) << 9)
                                           + (((kc << 6) + (quad << 4)) ^ rxor));
                accs[f] = __builtin_amdgcn_mfma_f32_16x16x32_bf16(qa, kf[kc], accs[f], 0, 0, 0);
            }
        }
        // P = exp(S/256): partial sums + cross-wave P bridge (dbuf, swizzled)
        unsigned char* pb = Pb0 + ((kt & 1) << 13);
#pragma unroll
        for (int f = 0; f < 4; ++f)
#pragma unroll
            for (int r = 0; r < 4; ++r) {
                float pe = __expf(accs[f][r] * (1.0f / 256.0f));
                l_acc[f][r] += pe;
                int q = f * 16 + quad * 4 + r;
                *(__bf16*)(pb + q * 128 + ((w * 32 + l15 * 2) ^ ((q & 7) << 4))) = (__bf16)pe;
            }
        // V fragments for this wave's 64 channels, direct from L2
        bf16x8 vf[4][2];
        {
            const unsigned short* vp = VpT + kt * 64;
#pragma unroll
            for (int ct2 = 0; ct2 < 4; ++ct2)
#pragma unroll
                for (int kc2 = 0; kc2 < 2; ++kc2)
                    vf[ct2][kc2] = *(const bf16x8*)(vp + (size_t)ct2 * 16 * NTOK + kc2 * 32);
        }
        __syncthreads();     // P(kt) visible to all waves
        // O += P @ V
#pragma unroll
        for (int kc2 = 0; kc2 < 2; ++kc2)
#pragma unroll
            for (int f = 0; f < 4; ++f) {
                bf16x8 pf = *(const bf16x8*)(pb + ((f * 16 + l15) << 7)
                                           + (((kc2 << 6) + (quad << 4)) ^ rxor));
#pragma unroll
                for (int ct2 = 0; ct2 < 4; ++ct2)
                    acc_o[f][ct2] = __builtin_amdgcn_mfma_f32_16x16x32_bf16(pf, vf[ct2][kc2], acc_o[f][ct2], 0, 0, 0);
            }
    }

    // row-sum finalize: reduce over l15 (16-lane groups), then across waves
#pragma unroll
    for (int f = 0; f < 4; ++f)
#pragma unroll
        for (int r = 0; r < 4; ++r) {
            float rs = l_acc[f][r];
            rs += __shfl_xor(rs, 1, 64);
            rs += __shfl_xor(rs, 2, 64);
            rs += __shfl_xor(rs, 4, 64);
            rs += __shfl_xor(rs, 8, 64);
            int q = f * 16 + quad * 4 + r;
            Ls[w * 64 + q] = rs;   // 16 lanes write same value — benign
        }
    __syncthreads();
    float l_tot[4][4];
#pragma unroll
    for (int f = 0; f < 4; ++f)
#pragma unroll
        for (int r = 0; r < 4; ++r) {
            int q = f * 16 + quad * 4 + r;
            l_tot[f][r] = Ls[q] + Ls[64 + q] + Ls[128 + q] + Ls[192 + q];
        }

    // epilogue: normalize + fp32 transpose in two 128-channel passes
    float* Ot = (float*)lds;   // [128][73] fp32 = 37376B (< Ls offset 49152)
    for (int p = 0; p < 2; ++p) {
        __syncthreads();
        if ((w >> 1) == p) {
            int wl = w & 1;
#pragma unroll
            for (int f = 0; f < 4; ++f)
#pragma unroll
                for (int ct2 = 0; ct2 < 4; ++ct2)
#pragma unroll
                    for (int r = 0; r < 4; ++r) {
                        float val = acc_o[f][ct2][r] / l_tot[f][r];
                        int cl = wl * 64 + ct2 * 16 + l15;
                        int q = f * 16 + quad * 4 + r;
                        Ot[cl * 73 + q] = val;
                    }
        }
        __syncthreads();
        for (int cg = 0; cg < 32; ++cg) {
            int cl = cg * 4 + w;
            int c = p * 128 + cl;
            Op[(size_t)c * NTOK + qt * 64 + lane] = Ot[cl * 73 + lane];
        }
    }
}

// ---------------------------------------------------------------------------
extern "C" void kernel_launch(void* const* d_in, const int* in_sizes, int n_in,
                              void* d_out, int out_size, void* d_ws, size_t ws_size,
                              hipStream_t stream) {
    (void)in_sizes; (void)n_in; (void)out_size; (void)ws_size;
    const float* feaL  = (const float*)d_in[0];
    const float* feaR  = (const float*)d_in[1];
    const float* Wq    = (const float*)d_in[2];
    const float* bq    = (const float*)d_in[3];
    const float* gq    = (const float*)d_in[4];
    const float* betaq = (const float*)d_in[5];
    const float* mq    = (const float*)d_in[6];
    const float* vq    = (const float*)d_in[7];
    const float* Wk    = (const float*)d_in[8];
    const float* bk    = (const float*)d_in[9];
    const float* gk    = (const float*)d_in[10];
    const float* betak = (const float*)d_in[11];
    const float* mk    = (const float*)d_in[12];
    const float* vk    = (const float*)d_in[13];

    // workspace (bf16): XT/VT alias 16*MATSZ (18.9MB) | Y 32*MATSZ (37.7MB)
    unsigned short* XT = (unsigned short*)d_ws;   // reused as VT after proj
    unsigned short* VT = XT;
    unsigned short* Yb = XT + (size_t)16 * MATSZ;
    float* out = (float*)d_out;   // fp32: reference output dtype

    dim3 blk(256);
    // XT[s][b][pos][c] = fea[b][c][pos]
    tpose_k<<<dim3(144, 16), blk, 0, stream>>>(feaL, feaR, XT, 256, 2304);
    proj_k<<<dim3(144, 32), blk, 0, stream>>>(XT, Wq, Wk, bq, bk, gq, gk,
                                              betaq, betak, mq, mk, vq, vk, Yb);
    // VT[s][b][c][n] = fea_flat[n*256+c]
    tpose_k<<<dim3(144, 16), blk, 0, stream>>>(feaL, feaR, VT, 2304, 256);
    attn_k<<<dim3(576), blk, 0, stream>>>(Yb, VT, out);
}

// Round 4
// 340.196 us; speedup vs baseline: 1.1994x; 1.1994x over previous
//
#include <hip/hip_runtime.h>

#define CH    256
#define NTOK  2304
#define MATSZ (CH * NTOK)   // 589824 elements per (b, matrix)

typedef __bf16 bf16x8 __attribute__((ext_vector_type(8)));
typedef float  f4v    __attribute__((ext_vector_type(4)));
typedef float  f16v   __attribute__((ext_vector_type(16)));
typedef unsigned int u32x4 __attribute__((ext_vector_type(4)));

__device__ __forceinline__ unsigned short f2bf(float f) {
    union { float f; unsigned int i; } c;
    c.f = f;
    unsigned int x = c.i;
    x += 0x7fffu + ((x >> 16) & 1u);   // round-to-nearest-even
    return (unsigned short)(x >> 16);
}

__device__ __forceinline__ bf16x8 cvt8(const float* p) {
    union { bf16x8 v; unsigned short s[8]; } u;
#pragma unroll
    for (int i = 0; i < 8; ++i) u.s[i] = f2bf(p[i]);
    return u.v;
}

// ---------------------------------------------------------------------------
// 64x64-tiled transpose + fp32->bf16 (unchanged — HW-verified)
// ---------------------------------------------------------------------------
__global__ __launch_bounds__(256) void tpose_k(
    const float* __restrict__ inL,
    const float* __restrict__ inR,
    unsigned short* __restrict__ out, int R, int Ccols)
{
    __shared__ unsigned short tile[64][72];
    int mat = blockIdx.y;
    const float* in = (mat >= 8 ? inR : inL) + (size_t)(mat & 7) * MATSZ;
    unsigned short* o = out + (size_t)mat * MATSZ;
    int tC = Ccols >> 6;
    int r0 = (blockIdx.x / tC) << 6;
    int c0 = (blockIdx.x % tC) << 6;
    int t = threadIdx.x;
    int col = t & 63, rs = t >> 6;
#pragma unroll
    for (int i = 0; i < 16; ++i) {
        int row = rs + i * 4;
        tile[row][col] = f2bf(in[(size_t)(r0 + row) * Ccols + c0 + col]);
    }
    __syncthreads();
#pragma unroll
    for (int i = 0; i < 16; ++i) {
        int crow = rs + i * 4;
        o[(size_t)(c0 + crow) * R + r0 + col] = tile[col][crow];
    }
}

// ---------------------------------------------------------------------------
// Projection (unchanged — HW-verified)
// ---------------------------------------------------------------------------
__global__ __launch_bounds__(256, 2) void proj_k(
    const unsigned short* __restrict__ XT,   // [2][8][2304][256] bf16
    const float* __restrict__ Wq_, const float* __restrict__ Wk_,
    const float* __restrict__ bq_, const float* __restrict__ bk_,
    const float* __restrict__ gq_, const float* __restrict__ gk_,
    const float* __restrict__ beq_, const float* __restrict__ bek_,
    const float* __restrict__ mq_, const float* __restrict__ mk_,
    const float* __restrict__ vq_, const float* __restrict__ vk_,
    unsigned short* __restrict__ Yout)       // [4][8][MATSZ] bf16
{
    __shared__ __align__(16) unsigned short Xs[64][264];
    int pb = blockIdx.y;
    int p = pb >> 3, b = pb & 7;
    int s = p & 1, br = p >> 1;
    const unsigned short* X = XT + (size_t)(s * 8 + b) * MATSZ;
    const float* W  = br ? Wk_ : Wq_;
    const float* bb = br ? bk_ : bq_;
    const float* gg = br ? gk_ : gq_;
    const float* be = br ? bek_ : beq_;
    const float* mm = br ? mk_ : mq_;
    const float* vv = br ? vk_ : vq_;
    unsigned short* Yo = Yout + (size_t)pb * MATSZ;

    int ot = blockIdx.x & 3, pt = blockIdx.x >> 2;
    int o0 = ot * 64, pos0 = pt * 64;
    int t = threadIdx.x;
    int w = t >> 6, lane = t & 63;
    int l15 = lane & 15, quad = lane >> 4;

    {   // stage XT tile: 64 pos-rows x 256 c
        int r = t >> 2, cq = (t & 3) << 6;
        const unsigned short* src = X + (size_t)(pos0 + r) * CH + cq;
        unsigned short* dst = &Xs[r][cq];
#pragma unroll
        for (int k = 0; k < 8; ++k)
            *(u32x4*)(dst + k * 8) = *(const u32x4*)(src + k * 8);
    }
    bf16x8 wf[8];
    {
        const float* wp = W + (size_t)(o0 + w * 16 + l15) * CH + quad * 8;
#pragma unroll
        for (int kc = 0; kc < 8; ++kc)
            wf[kc] = cvt8(wp + kc * 32);
    }
    __syncthreads();

    f4v zero4 = {0.f, 0.f, 0.f, 0.f};
    f4v acc[4] = {zero4, zero4, zero4, zero4};
#pragma unroll
    for (int kc = 0; kc < 8; ++kc) {
#pragma unroll
        for (int ct = 0; ct < 4; ++ct) {
            bf16x8 xb = *(const bf16x8*)(&Xs[ct * 16 + l15][kc * 32 + quad * 8]);
            acc[ct] = __builtin_amdgcn_mfma_f32_16x16x32_bf16(wf[kc], xb, acc[ct], 0, 0, 0);
        }
    }
#pragma unroll
    for (int r = 0; r < 4; ++r) {
        int o = o0 + w * 16 + quad * 4 + r;
        float scale = gg[o] * rsqrtf(vv[o] + 1e-5f);
        float shift = (bb[o] - mm[o]) * scale + be[o];
#pragma unroll
        for (int ct = 0; ct < 4; ++ct) {
            float val = acc[ct][r] * scale + shift;
            Yo[(size_t)o * NTOK + pos0 + ct * 16 + l15] = f2bf(val);
        }
    }
}

// ---------------------------------------------------------------------------
// Fused attention R4: 32x32x16 MFMAs (2x FLOP per LDS fragment byte),
// global_load_lds staging, q-tile 64, KVBLK 64, 3 barriers/tile.
//
//  * LDS layouts (identical swizzle family to R2, HW-verified):
//      Ks [64 key][512B]  phys = key*512 + (off ^ ((key&7)<<4))
//      Vs [256 ch][128B]  phys = ch*128  + (off ^ ((ch&7)<<4))
//      Pb [64 q ][128B]   phys = q*128   + (off ^ ((q&7)<<4))
//  * Staging: LINEAR LDS dest (wave-uniform base + lane*16, glld-compatible)
//    with INVERSE-swizzled global source: LDS[p] = G[p ^ swz(row(p))].
//    Swizzle row-bits are k-iteration-invariant (rows advance by 8/32 per
//    iter), so the per-thread source offset is constant + k*stride.
//    Verified: K key=9,ch=0: p=4624 <- src 4608 = logical; read kf(key=9)
//    at 4608^16=4624 ✓. V ch=5: p=720 <- src VT[5][0] ✓ read at 720 ✓.
//  * QK^T: wave (qb=w>>1, kb=w&1) -> one 32x32 S block, 16 k-steps, Q in
//    regs (A-frag row=l31, k=h*8+j). exp + per-lane l_acc + P write.
//  * PV: wave (qb=w>>1, chh=w&1) -> O[32q][128ch], P as A from Pb.
//  * C-layout (m74/m101): col=lane&31, row=(r&3)+8*(r>>2)+4*h. l_acc[r]
//    rows align with acc_o[r] rows -> register-divide normalization;
//    kb-partner sums merged through tiny Ls patch.
// ---------------------------------------------------------------------------
__global__ __launch_bounds__(256, 2) void attn_k(
    const unsigned short* __restrict__ Y,    // [4][8][MATSZ] projections bf16
    const unsigned short* __restrict__ VT,   // [2][8][256][2304] bf16
    float* __restrict__ out)                 // [2][8][MATSZ] fp32
{
    __shared__ __align__(16) unsigned char lds[74240];
    unsigned char* Ks = lds;                    // 32768
    unsigned char* Vs = lds + 32768;            // 32768
    unsigned char* Pb = lds + 65536;            // 8192
    float*         Ls = (float*)(lds + 73728);  // [4][32] f32

    int bid = blockIdx.x;
    int wg = (bid & 7) * 72 + (bid >> 3);   // XCD swizzle (576 = 8*72, bijective)
    int qt = wg % 36;
    int ab = wg / 36;
    int a = ab >> 3, b = ab & 7;
    const unsigned short* Qp = Y + (size_t)(a * 8 + b) * MATSZ;        // q(l)/q(r)
    const unsigned short* Kp = Y + (size_t)((3 - a) * 8 + b) * MATSZ;  // k(r)/k(l)
    const unsigned short* Vp = VT + (size_t)((1 - a) * 8 + b) * MATSZ;
    float* Op = out + (size_t)ab * MATSZ;

    int t = threadIdx.x;
    int w = t >> 6, lane = t & 63;
    int l31 = lane & 31, h = lane >> 5;
    int qb = w >> 1;             // q-block (QK^T and PV)
    int kb = w & 1;              // key-block (QK^T)
    int chh = w & 1;             // channel-half (PV)
    int rxor = (l31 & 7) << 4;   // read-side swizzle (row&7 == l31&7 everywhere)

    // staging addresses: linear LDS dest, inverse-swizzled global source
    const unsigned char* kS = (const unsigned char*)Kp
        + ((t * 16) ^ (((t >> 5) & 7) << 4));                 // + kt*32768 + k*4096
    const unsigned char* vS = (const unsigned char*)Vp
        + (size_t)(t >> 3) * 4608
        + (((t & 7) * 16) ^ (((t >> 3) & 7) << 4));           // + kt*128 + k*147456
    unsigned char* kD = Ks + t * 16;                          // + k*4096
    unsigned char* vD = Vs + t * 16;                          // + k*4096

    // Q fragments in registers: rows qt*64 + qb*32 + l31, A-frag k = h*8+j
    bf16x8 qf[16];
    {
        const unsigned short* qp = Qp + (size_t)(qt * 64 + qb * 32 + l31) * CH + h * 8;
#pragma unroll
        for (int ks = 0; ks < 16; ++ks)
            qf[ks] = *(const bf16x8*)(qp + ks * 16);
    }

    f16v acc_o[4];
#pragma unroll
    for (int c = 0; c < 4; ++c)
#pragma unroll
        for (int r = 0; r < 16; ++r) acc_o[c][r] = 0.f;
    float l_acc[16];
#pragma unroll
    for (int r = 0; r < 16; ++r) l_acc[r] = 0.f;

    for (int kt = 0; kt < 36; ++kt) {
        __syncthreads();   // readers of tile kt-1 done (Ks, Vs, Pb)
#pragma unroll
        for (int k = 0; k < 8; ++k)
            __builtin_amdgcn_global_load_lds(
                (const unsigned int*)(kS + (size_t)kt * 32768 + k * 4096),
                (unsigned int*)(kD + k * 4096), 16, 0, 0);
#pragma unroll
        for (int k = 0; k < 8; ++k)
            __builtin_amdgcn_global_load_lds(
                (const unsigned int*)(vS + (size_t)kt * 128 + (size_t)k * 147456),
                (unsigned int*)(vD + k * 4096), 16, 0, 0);
        __syncthreads();   // staged tile visible (syncthreads drains vmcnt)

        // ---- QK^T: S[qb*32..+32][kb*32..+32], 16 dependent k-steps
        f16v accs;
#pragma unroll
        for (int r = 0; r < 16; ++r) accs[r] = 0.f;
        const unsigned char* krow = Ks + ((kb * 32 + l31) << 9);
#pragma unroll
        for (int ks = 0; ks < 16; ++ks) {
            bf16x8 kf = *(const bf16x8*)(krow + ((ks * 32 + h * 16) ^ rxor));
            accs = __builtin_amdgcn_mfma_f32_32x32x16_bf16(qf[ks], kf, accs, 0, 0, 0);
        }
        // ---- exp, partial row-sums, P write (C-layout row=(r&3)+8*(r>>2)+4h)
#pragma unroll
        for (int r = 0; r < 16; ++r) {
            float pe = __expf(accs[r] * (1.0f / 256.0f));
            l_acc[r] += pe;
            int row = (r & 3) + 8 * (r >> 2) + 4 * h;   // q within qb*32
            int q = qb * 32 + row;
            *(__bf16*)(Pb + q * 128 + ((kb * 64 + l31 * 2) ^ ((row & 7) << 4))) = (__bf16)pe;
        }
        __syncthreads();   // P(kt) visible to all waves

        // ---- PV: O[qb*32..+32][chh*128..+128]
#pragma unroll
        for (int ks2 = 0; ks2 < 4; ++ks2) {
            bf16x8 pf = *(const bf16x8*)(Pb + ((qb * 32 + l31) << 7)
                                       + ((ks2 * 32 + h * 16) ^ rxor));
#pragma unroll
            for (int chb = 0; chb < 4; ++chb) {
                int ch = chh * 128 + chb * 32 + l31;
                bf16x8 vf = *(const bf16x8*)(Vs + (ch << 7)
                                           + ((ks2 * 32 + h * 16) ^ rxor));
                acc_o[chb] = __builtin_amdgcn_mfma_f32_32x32x16_bf16(pf, vf, acc_o[chb], 0, 0, 0);
            }
        }
    }

    // ---- row-sum finalize: reduce over the 32 key-lanes (within each half)
#pragma unroll
    for (int r = 0; r < 16; ++r) {
        float rs = l_acc[r];
        rs += __shfl_xor(rs, 1, 64);
        rs += __shfl_xor(rs, 2, 64);
        rs += __shfl_xor(rs, 4, 64);
        rs += __shfl_xor(rs, 8, 64);
        rs += __shfl_xor(rs, 16, 64);
        l_acc[r] = rs;
    }
    if (l31 == 0) {   // lanes 0 and 32 publish their half's 16 rows
#pragma unroll
        for (int r = 0; r < 16; ++r) {
            int row = (r & 3) + 8 * (r >> 2) + 4 * h;
            Ls[w * 32 + row] = l_acc[r];
        }
    }
    __syncthreads();   // Ls visible; also fences last PV reads before Ot reuse
    float l_tot[16];
#pragma unroll
    for (int r = 0; r < 16; ++r) {
        int row = (r & 3) + 8 * (r >> 2) + 4 * h;
        l_tot[r] = Ls[w * 32 + row] + Ls[(w ^ 1) * 32 + row];  // kb0 + kb1
    }

    // ---- epilogue: normalize, swizzled fp32 transpose, coalesced stores
    float* Ot = (float*)lds;   // [256 ch][64 q] f32, dword-XOR ((c&7)<<2)
#pragma unroll
    for (int chb = 0; chb < 4; ++chb) {
        int c = chh * 128 + chb * 32 + l31;
        int cx = (c & 7) << 2;
#pragma unroll
        for (int rr = 0; rr < 4; ++rr) {
            f4v v4;
#pragma unroll
            for (int i = 0; i < 4; ++i)
                v4[i] = acc_o[chb][rr * 4 + i] / l_tot[rr * 4 + i];
            int q0 = qb * 32 + rr * 8 + h * 4;   // rows rr*8+{0..3}+4h consecutive
            *(f4v*)(Ot + c * 64 + (q0 ^ cx)) = v4;
        }
    }
    __syncthreads();
#pragma unroll
    for (int p = 0; p < 16; ++p) {
        int c = p * 16 + (t >> 4);
        int q = (t & 15) * 4;
        f4v v4 = *(const f4v*)(Ot + c * 64 + (q ^ ((c & 7) << 2)));
        *(f4v*)(Op + (size_t)c * NTOK + qt * 64 + q) = v4;
    }
}

// ---------------------------------------------------------------------------
extern "C" void kernel_launch(void* const* d_in, const int* in_sizes, int n_in,
                              void* d_out, int out_size, void* d_ws, size_t ws_size,
                              hipStream_t stream) {
    (void)in_sizes; (void)n_in; (void)out_size; (void)ws_size;
    const float* feaL  = (const float*)d_in[0];
    const float* feaR  = (const float*)d_in[1];
    const float* Wq    = (const float*)d_in[2];
    const float* bq    = (const float*)d_in[3];
    const float* gq    = (const float*)d_in[4];
    const float* betaq = (const float*)d_in[5];
    const float* mq    = (const float*)d_in[6];
    const float* vq    = (const float*)d_in[7];
    const float* Wk    = (const float*)d_in[8];
    const float* bk    = (const float*)d_in[9];
    const float* gk    = (const float*)d_in[10];
    const float* betak = (const float*)d_in[11];
    const float* mk    = (const float*)d_in[12];
    const float* vk    = (const float*)d_in[13];

    // workspace (bf16): XT/VT alias 16*MATSZ (18.9MB) | Y 32*MATSZ (37.7MB)
    unsigned short* XT = (unsigned short*)d_ws;   // reused as VT after proj
    unsigned short* VT = XT;
    unsigned short* Yb = XT + (size_t)16 * MATSZ;
    float* out = (float*)d_out;   // fp32: reference output dtype

    dim3 blk(256);
    // XT[s][b][pos][c] = fea[b][c][pos]
    tpose_k<<<dim3(144, 16), blk, 0, stream>>>(feaL, feaR, XT, 256, 2304);
    proj_k<<<dim3(144, 32), blk, 0, stream>>>(XT, Wq, Wk, bq, bk, gq, gk,
                                              betaq, betak, mq, mk, vq, vk, Yb);
    // VT[s][b][c][n] = fea_flat[n*256+c]
    tpose_k<<<dim3(144, 16), blk, 0, stream>>>(feaL, feaR, VT, 2304, 256);
    attn_k<<<dim3(576), blk, 0, stream>>>(Yb, VT, out);
}